// Round 2
// baseline (566.176 us; speedup 1.0000x reference)
//
#include <hip/hip_runtime.h>

// B=8, S=1024, MD=1024, H=16, D=64. SCALE = (64//16)^-0.5 = 0.5.
// Inputs fp32, OUTPUTS fp32. Internal pipeline bf16 MFMA, fp32 accumulate.
// torch .view(B*H,-1,D) = flat row-major reinterpretation: attention over
// [G=128][T=1024][D=64] with flat pointer math.
//
// R1->R2: attn was latency-bound at 2 blocks/CU (Occupancy 23%, all pipes
// <21%). Split heads across 2 blocks (1024 blocks = 4/CU), shrink LDS to
// 34 KB (wave-private P strips, ctx-partial aliased into them) so 4 blocks
// fit, attn_post summed across the 2 head-groups via zero-fill + atomicAdd
// (2 commutative adds/address => deterministic). QKV GEMMs merged into one
// grid.z=3 dispatch (1536 blocks) for the same occupancy reason.

typedef __attribute__((ext_vector_type(8))) short bf16x8;
typedef __attribute__((ext_vector_type(4))) float f32x4;
typedef __attribute__((ext_vector_type(4))) int int4v;

static __device__ __forceinline__ short f2bf(float f) {
  union { float f; unsigned u; } v; v.f = f;
  unsigned lsb = (v.u >> 16) & 1u;
  v.u += 0x7fffu + lsb;
  return (short)(v.u >> 16);
}

// async global->LDS, 16B per lane; LDS dest = wave-uniform base + lane*16
#define GLDS16(gp, lp) __builtin_amdgcn_global_load_lds( \
    (const __attribute__((address_space(1))) void*)(gp), \
    (__attribute__((address_space(3))) void*)(lp), 16, 0, 0)

struct Ptr4 { const float* s[4]; short* d[4]; };
struct Ptr3 { const float* s[3]; short* d[3]; };
struct QkvArgs { const short* A[3]; const short* B[3]; const float* bias[3]; short* C[3]; };

// ---------- fp32 W[k][n] -> bf16 WT[n][k], 64x64 tiles; z selects matrix ----
__global__ __launch_bounds__(256) void convt4(Ptr4 a)
{
  const float* __restrict__ src = a.s[blockIdx.z];
  short* __restrict__ dst = a.d[blockIdx.z];
  __shared__ float T[64][65];
  const int tid = threadIdx.x;
  const int c0 = blockIdx.x * 64, r0 = blockIdx.y * 64;
  {
    const int rr = tid >> 4, cc = (tid & 15) * 4;
    for (int i = 0; i < 4; ++i) {
      int row = rr + i * 16;
      const float4 v = *(const float4*)(src + (size_t)(r0 + row) * 1024 + c0 + cc);
      T[row][cc] = v.x; T[row][cc + 1] = v.y; T[row][cc + 2] = v.z; T[row][cc + 3] = v.w;
    }
  }
  __syncthreads();
  {
    const int rr = tid >> 3, cc = (tid & 7) * 8;
    for (int i = 0; i < 2; ++i) {
      int row = rr + i * 32;             // dst row within tile (= src col)
      bf16x8 v;
      for (int j = 0; j < 8; ++j) v[j] = f2bf(T[cc + j][row]);
      *(bf16x8*)(dst + (size_t)(c0 + row) * 1024 + r0 + cc) = v;
    }
  }
}

// ---------- fp32 -> bf16 elementwise; z selects tensor ----------
// grid.x * 256 * 8 == 8M exactly, no bounds check needed.
__global__ __launch_bounds__(256) void cvt3(Ptr3 a)
{
  const float* __restrict__ src = a.s[blockIdx.z];
  short* __restrict__ dst = a.d[blockIdx.z];
  const size_t i = ((size_t)blockIdx.x * 256 + threadIdx.x) * 8;
  const float4 v0 = *(const float4*)(src + i);
  const float4 v1 = *(const float4*)(src + i + 4);
  bf16x8 o;
  o[0] = f2bf(v0.x); o[1] = f2bf(v0.y); o[2] = f2bf(v0.z); o[3] = f2bf(v0.w);
  o[4] = f2bf(v1.x); o[5] = f2bf(v1.y); o[6] = f2bf(v1.z); o[7] = f2bf(v1.w);
  *(bf16x8*)(dst + i) = o;
}

// ---------- zero fill fp32 (for attn_post atomic accumulation) ----------
// grid 2048: 2048*256*16 = 8M floats exactly.
__global__ __launch_bounds__(256) void zero_f32(float* __restrict__ p)
{
  const size_t i = ((size_t)blockIdx.x * 256 + threadIdx.x) * 16;
  const float4 z = {0.f, 0.f, 0.f, 0.f};
  *(float4*)(p + i) = z; *(float4*)(p + i + 4) = z;
  *(float4*)(p + i + 8) = z; *(float4*)(p + i + 12) = z;
}

// ---------- per-g 64x64 bf16 tile transpose: V[g][t][d] -> VpT[g][d][t] ----
__global__ __launch_bounds__(256) void transp_v(
    const short* __restrict__ src, short* __restrict__ dst)
{
  __shared__ short T[64][72];
  const int g = blockIdx.y, t0 = blockIdx.x * 64;
  const short* s = src + (size_t)g * 65536 + (size_t)t0 * 64;
  short* d = dst + (size_t)g * 65536 + t0;
  const int r = threadIdx.x >> 3, c = (threadIdx.x & 7) * 8;
  for (int i = 0; i < 2; ++i) {
    bf16x8 v = *(const bf16x8*)(s + (size_t)(r + i * 32) * 64 + c);
    *(bf16x8*)(&T[r + i * 32][c]) = v;
  }
  __syncthreads();
  for (int i = 0; i < 2; ++i) {
    int dr = r + i * 32;                 // d index
    bf16x8 v;
    for (int j = 0; j < 8; ++j) v[j] = T[c + j][dr];
    *(bf16x8*)(d + (size_t)dr * 1024 + c) = v;
  }
}

// ---------- GEMM body: C[8192,1024] = A[8192,1024](bf16) * BT[1024,1024]^T + bias
// m97 structure: 128x128 tile, BK=64, global_load_lds width-16 into linear LDS.
// mode: 0 = bf16 store; 2 = fp32 store (final output).
static __device__ __forceinline__ void gemm_body(
    const short* __restrict__ A, const short* __restrict__ BT,
    const float* __restrict__ bias, void* __restrict__ Cp, int mode)
{
  __shared__ short As[128 * 64];
  __shared__ short Bs[128 * 64];
  const int K = 1024, N = 1024;
  const int tid = threadIdx.x;
  const int lane = tid & 63, wave = tid >> 6;
  const int quad = lane >> 4, l16 = lane & 15;
  const int wm = (wave & 1) * 64, wn = (wave >> 1) * 64;
  const int bm = blockIdx.x * 128, bn = blockIdx.y * 128;

  f32x4 acc[4][4] = {};

  const int s_row = tid >> 3;            // 0..31
  const int s_col = (tid & 7) * 8;       // 0..56 (shorts)
  const int lds_base = wave * 512;       // wave-uniform (shorts)

  for (int k0 = 0; k0 < K; k0 += 64) {
    for (int i = 0; i < 4; ++i) {
      int row = s_row + i * 32;
      GLDS16(A + (size_t)(bm + row) * K + k0 + s_col, &As[i * 2048 + lds_base]);
      GLDS16(BT + (size_t)(bn + row) * K + k0 + s_col, &Bs[i * 2048 + lds_base]);
    }
    __syncthreads();
    for (int ks = 0; ks < 2; ++ks) {
      bf16x8 af[4], bfr[4];
      for (int mi = 0; mi < 4; ++mi)
        af[mi] = *(const bf16x8*)(&As[(wm + mi * 16 + l16) * 64 + ks * 32 + quad * 8]);
      for (int ni = 0; ni < 4; ++ni)
        bfr[ni] = *(const bf16x8*)(&Bs[(wn + ni * 16 + l16) * 64 + ks * 32 + quad * 8]);
      for (int mi = 0; mi < 4; ++mi)
        for (int ni = 0; ni < 4; ++ni)
          acc[mi][ni] = __builtin_amdgcn_mfma_f32_16x16x32_bf16(af[mi], bfr[ni], acc[mi][ni], 0, 0, 0);
    }
    __syncthreads();
  }

  for (int ni = 0; ni < 4; ++ni) {
    int col = bn + wn + ni * 16 + l16;
    float bv = bias[col];
    for (int mi = 0; mi < 4; ++mi) {
      int row0 = bm + wm + mi * 16 + quad * 4;   // C row = quad*4+reg
      for (int r = 0; r < 4; ++r) {
        int row = row0 + r;
        float fv = acc[mi][ni][r] + bv;
        if (mode == 2) ((float*)Cp)[(size_t)row * N + col] = fv;
        else           ((short*)Cp)[(size_t)row * N + col] = f2bf(fv);
      }
    }
  }
}

__global__ __launch_bounds__(256) void gemm_bt16(
    const short* __restrict__ A, const short* __restrict__ BT,
    const float* __restrict__ bias, void* __restrict__ Cp, int mode)
{
  gemm_body(A, BT, bias, Cp, mode);
}

// combined Q/K/V projection: grid.z selects which GEMM
__global__ __launch_bounds__(256) void gemm_qkv(QkvArgs a)
{
  const int z = blockIdx.z;
  gemm_body(a.A[z], a.B[z], a.bias[z], a.C[z], 0);
}

// ---------- fused attention over [G=128,T=1024,D=64] ----------
// block = (b, 16-row t-tile, head-group of 8); 4 waves split s into 256-wide
// strips. P strips are wave-private LDS; ctx partial aliases the same strip
// (written only after the wave's last P read; barriers separate phases).
// attn_post accumulated across the 2 head-groups via atomicAdd (pre-zeroed).
// No max-subtraction: scores ~N(0,16), |x|<~35 => exp safe in fp32.
__global__ __launch_bounds__(256) void attn_fused2(
    const short* __restrict__ Qp, const short* __restrict__ Kp,
    const short* __restrict__ VpT,               // [g][d][t]
    short* __restrict__ ctx,                     // [g][t][d] flat (bf16)
    float* __restrict__ attn_post)               // [b][t][s] FP32, atomic
{
  __shared__ short Pw[4][16][264];               // per-wave 16 x 256 (+8 pad)
  __shared__ float red[16][4];

  const int tid = threadIdx.x;
  const int wave = tid >> 6, lane = tid & 63;
  const int quad = lane >> 4, l16 = lane & 15;
  const int hg = blockIdx.x & 1;
  const int t0 = ((blockIdx.x >> 1) & 63) * 16;
  const int b = blockIdx.x >> 7;
  const int sbase = wave * 256;

  float sig[16][4] = {};                         // sigmoid acc over 8 heads

  for (int h = hg * 8; h < hg * 8 + 8; ++h) {
    const int g = b * 16 + h;
    const short* Qg = Qp + (size_t)g * 65536;
    const short* Kg = Kp + (size_t)g * 65536;
    const short* Vg = VpT + (size_t)g * 65536;

    bf16x8 aq0 = *(const bf16x8*)(Qg + (t0 + l16) * 64 + quad * 8);
    bf16x8 aq1 = *(const bf16x8*)(Qg + (t0 + l16) * 64 + 32 + quad * 8);

    float sc[16][4];                             // holds e^x
    float rsum[4] = {0.f, 0.f, 0.f, 0.f};
    for (int tile = 0; tile < 16; ++tile) {
      int s = sbase + tile * 16;
      bf16x8 bk0 = *(const bf16x8*)(Kg + (s + l16) * 64 + quad * 8);
      bf16x8 bk1 = *(const bf16x8*)(Kg + (s + l16) * 64 + 32 + quad * 8);
      f32x4 c = {0.f, 0.f, 0.f, 0.f};
      c = __builtin_amdgcn_mfma_f32_16x16x32_bf16(aq0, bk0, c, 0, 0, 0);
      c = __builtin_amdgcn_mfma_f32_16x16x32_bf16(aq1, bk1, c, 0, 0, 0);
      for (int r = 0; r < 4; ++r) {
        float x = c[r] * 0.5f;                   // SCALE = 0.5
        float e = __expf(x);
        sc[tile][r] = e;
        rsum[r] += e;
        sig[tile][r] += e * __builtin_amdgcn_rcpf(1.f + e);   // sigmoid(x)
      }
    }
    for (int r = 0; r < 4; ++r)
      for (int mask = 1; mask < 16; mask <<= 1) rsum[r] += __shfl_xor(rsum[r], mask, 64);
    if (l16 == 0)
      for (int r = 0; r < 4; ++r) red[quad * 4 + r][wave] = rsum[r];
    __syncthreads();                             // B1
    for (int r = 0; r < 4; ++r) {
      int row = quad * 4 + r;
      float s4 = red[row][0] + red[row][1] + red[row][2] + red[row][3];
      float inv = __builtin_amdgcn_rcpf(s4);
      for (int tile = 0; tile < 16; ++tile)
        Pw[wave][row][tile * 16 + l16] = f2bf(sc[tile][r] * inv);
    }
    f32x4 cacc[4] = {};
    for (int ks = 0; ks < 8; ++ks) {
      bf16x8 ap = *(const bf16x8*)(&Pw[wave][l16][ks * 32 + quad * 8]);
      for (int ni = 0; ni < 4; ++ni) {
        bf16x8 bv = *(const bf16x8*)(Vg + (ni * 16 + l16) * 1024 + sbase + ks * 32 + quad * 8);
        cacc[ni] = __builtin_amdgcn_mfma_f32_16x16x32_bf16(ap, bv, cacc[ni], 0, 0, 0);
      }
    }
    // ctx partial: alias this wave's P strip (16x64 f32 = 4KB <= 8448B strip).
    // Safe: all of this wave's P reads precede these writes in program order.
    {
      float* cw = (float*)(&Pw[wave][0][0]);
      for (int ni = 0; ni < 4; ++ni)
        for (int r = 0; r < 4; ++r)
          cw[(quad * 4 + r) * 64 + ni * 16 + l16] = cacc[ni][r];
    }
    __syncthreads();                             // B2
    short* ctxg = ctx + (size_t)g * 65536 + t0 * 64;
    for (int e = tid; e < 1024; e += 256) {
      int t = e >> 6, dd = e & 63;
      float v = ((float*)(&Pw[0][0][0]))[t * 64 + dd]
              + ((float*)(&Pw[1][0][0]))[t * 64 + dd]
              + ((float*)(&Pw[2][0][0]))[t * 64 + dd]
              + ((float*)(&Pw[3][0][0]))[t * 64 + dd];
      ctxg[t * 64 + dd] = f2bf(v);
    }
    // Next head's P-strip writes happen only after its B1 -> no hazard with
    // this head's cross-wave ctx reads (which precede B1 in program order).
  }

  float* ap_out = attn_post + (size_t)b * 1048576 + (size_t)t0 * 1024;
  for (int tile = 0; tile < 16; ++tile)
    for (int r = 0; r < 4; ++r)
      atomicAdd(&ap_out[(quad * 4 + r) * 1024 + sbase + tile * 16 + l16],
                sig[tile][r] * 0.0625f);
}

extern "C" void kernel_launch(void* const* d_in, const int* in_sizes, int n_in,
                              void* d_out, int out_size, void* d_ws, size_t ws_size,
                              hipStream_t stream) {
  const float* query = (const float*)d_in[0];
  const float* key   = (const float*)d_in[1];
  const float* value = (const float*)d_in[2];
  const float* Wq = (const float*)d_in[3]; const float* bq = (const float*)d_in[4];
  const float* Wk = (const float*)d_in[5]; const float* bk = (const float*)d_in[6];
  const float* Wv = (const float*)d_in[7]; const float* bv = (const float*)d_in[8];
  const float* Wo = (const float*)d_in[9]; const float* bo = (const float*)d_in[10];

  float* out0 = (float*)d_out;              // [8,1024,1024] fp32
  float* attn_post = out0 + (8u << 20);     // [8,1024,1024] fp32

  // common workspace head: 4 x 1M weightT + 3 x 8M (Qp,Kp,VpT)
  short* WqT = (short*)d_ws;
  short* WkT = WqT + (1u << 20);
  short* WvT = WkT + (1u << 20);
  short* WoT = WvT + (1u << 20);
  short* Qp  = WoT + (1u << 20);
  short* Kp  = Qp + (8u << 20);
  short* VpT = Kp + (8u << 20);

  dim3 blk(256);
  const size_t NEED_BIG = (size_t)(60u << 20) * 2;   // 120 MiB

  convt4<<<dim3(16, 16, 4), blk, 0, stream>>>(
      Ptr4{{Wq, Wk, Wv, Wo}, {WqT, WkT, WvT, WoT}});
  zero_f32<<<dim3(2048), blk, 0, stream>>>(attn_post);

  short* ctx;
  if (ws_size >= NEED_BIG) {
    // big layout: + Xq,Xk,Xv (3 x 8M) + Vflat (8M) = 60M shorts total
    short* Xq = VpT + (8u << 20);
    short* Xk = Xq + (8u << 20);
    short* Xv = Xk + (8u << 20);
    short* Vflat = Xv + (8u << 20);
    ctx = Xq;                                      // dead after qkv GEMM

    cvt3<<<dim3(4096, 1, 3), blk, 0, stream>>>(Ptr3{{query, key, value}, {Xq, Xk, Xv}});
    gemm_qkv<<<dim3(64, 8, 3), blk, 0, stream>>>(
        QkvArgs{{Xq, Xk, Xv}, {WqT, WkT, WvT}, {bq, bk, bv}, {Qp, Kp, Vflat}});
    transp_v<<<dim3(16, 128), blk, 0, stream>>>(Vflat, VpT);
  } else {
    // small layout (88 MB, proven): Xin (8M) + Vflat (8M), sequential
    short* Xin = VpT + (8u << 20);
    short* Vflat = Xin + (8u << 20);
    ctx = Xin;

    cvt3<<<dim3(4096, 1, 1), blk, 0, stream>>>(Ptr3{{query, query, query}, {Xin, Xin, Xin}});
    gemm_bt16<<<dim3(64, 8), blk, 0, stream>>>(Xin, WqT, bq, Qp, 0);
    cvt3<<<dim3(4096, 1, 1), blk, 0, stream>>>(Ptr3{{key, key, key}, {Xin, Xin, Xin}});
    gemm_bt16<<<dim3(64, 8), blk, 0, stream>>>(Xin, WkT, bk, Kp, 0);
    cvt3<<<dim3(4096, 1, 1), blk, 0, stream>>>(Ptr3{{value, value, value}, {Xin, Xin, Xin}});
    gemm_bt16<<<dim3(64, 8), blk, 0, stream>>>(Xin, WvT, bv, Vflat, 0);
    transp_v<<<dim3(16, 128), blk, 0, stream>>>(Vflat, VpT);
  }

  attn_fused2<<<dim3(1024), blk, 0, stream>>>(Qp, Kp, VpT, ctx, attn_post);
  gemm_bt16<<<dim3(64, 8), blk, 0, stream>>>(ctx, WoT, bo, out0, 2);
}